// Round 1
// baseline (142.921 us; speedup 1.0000x reference)
//
#include <hip/hip_runtime.h>
#include <hip/hip_bf16.h>
#include <stdint.h>

// Problem constants
// x: [16,128,56,56] f32, w: [256,128,3,3] f32, bias: [256] f32
// out: [16,256,56,56] f32
// Implicit GEMM: M=Cout=256, N=pixels=50176, K=C*9=1152 (order: (kh*3+kw), c)

typedef __attribute__((ext_vector_type(8))) short short8;
typedef __attribute__((ext_vector_type(4))) float floatx4;

__device__ static inline void gload_lds16(const void* g, void* l) {
  typedef const __attribute__((address_space(1))) unsigned int* gp_t;
  typedef __attribute__((address_space(3))) unsigned int* lp_t;
  // low 32 bits of a generic LDS pointer are the LDS offset (aperture in high bits)
  __builtin_amdgcn_global_load_lds((gp_t)(uintptr_t)g, (lp_t)(uint32_t)(uintptr_t)l,
                                   16, 0, 0);
}

// ---------- pass 1a: x NCHW f32 -> padded NHWC bf16 (xp[16][58][58][128]) ----------
__global__ __launch_bounds__(256)
void xpose_kernel(const float* __restrict__ x, __hip_bfloat16* __restrict__ xp) {
  const int n = blockIdx.x / 56;
  const int h = blockIdx.x % 56;
  __shared__ float tile[128][57];  // +1 pad breaks bank conflicts
  const float* src = x + (size_t)n * (128 * 3136) + h * 56;  // + c*3136 + w
  for (int idx = threadIdx.x; idx < 128 * 56; idx += 256) {
    const int c = idx / 56, w = idx - c * 56;
    tile[c][w] = src[(size_t)c * 3136 + w];
  }
  __syncthreads();
  // dst row (n, h+1), col offset 1 (halo pre-zeroed by memset)
  __hip_bfloat16* dst = xp + ((size_t)(n * 58 + h + 1) * 58 + 1) * 128;
  for (int idx = threadIdx.x; idx < 56 * 64; idx += 256) {
    const int w = idx >> 6, c2 = idx & 63;
    union { unsigned u; __hip_bfloat16 h2[2]; } pk;
    pk.h2[0] = __float2bfloat16(tile[2 * c2][w]);
    pk.h2[1] = __float2bfloat16(tile[2 * c2 + 1][w]);
    *(unsigned*)(dst + (size_t)w * 128 + 2 * c2) = pk.u;
  }
}

// ---------- pass 1b: weight [256][128][3][3] f32 -> wt[256][9][128] bf16 ----------
__global__ __launch_bounds__(256)
void wxf_kernel(const float* __restrict__ wsrc, __hip_bfloat16* __restrict__ wt) {
  const int t = blockIdx.x * 256 + threadIdx.x;
  if (t >= 256 * 9 * 128) return;
  const int c = t & 127;
  const int kq = (t >> 7) % 9;
  const int cout = t / (9 * 128);
  wt[t] = __float2bfloat16(wsrc[(size_t)(cout * 128 + c) * 9 + kq]);
}

// ---------- main implicit-GEMM MFMA kernel ----------
// Block: 256 threads = 4 waves (2x2), tile 128(M) x 128(N), BK=64 (half a tap's C)
// LDS rows are 64 ch = 128 B = 8 x 16B chunks; chunk q stored at position q ^ (row&7)
// (swizzle applied via the *global* source address; global_load_lds LDS dest is fixed).
__global__ __launch_bounds__(256)
void conv_gemm_kernel(const __hip_bfloat16* __restrict__ xp,
                      const __hip_bfloat16* __restrict__ wt,
                      const float* __restrict__ bias,
                      float* __restrict__ out) {
  __shared__ __align__(16) __hip_bfloat16 As[128 * 64];  // [m][k] 16 KB
  __shared__ __align__(16) __hip_bfloat16 Bs[128 * 64];  // [n][k] 16 KB

  const int tid = threadIdx.x;
  const int lane = tid & 63;
  const int wave = tid >> 6;
  const int wm = wave >> 1, wn = wave & 1;
  const int m0 = blockIdx.y * 128;  // 0 or 128
  const int n0 = blockIdx.x * 128;  // pixel tile base (392 tiles, exact)

  // -------- staging descriptors: 4 insts per 16KB tile, 256 thr x 16B --------
  const char* wtb = (const char*)wt;
  const char* xpb = (const char*)xp;
  const char* gA[4];
  const char* gB[4];
  char* lA[4];
  char* lB[4];
#pragma unroll
  for (int i = 0; i < 4; ++i) {
    const int f = (i * 256 + tid) * 16;        // byte offset in tile
    const int row = f >> 7;                    // tile row (128 B per row)
    const int sub = (f >> 4) & 7;              // 16B chunk position in row
    const int cb = (sub ^ (row & 7)) << 4;     // swizzled source chunk byte
    // A: wt[m0+row][kq][chunk*64 + ...]; row stride 9*128*2 = 2304 B
    gA[i] = wtb + (size_t)(m0 + row) * 2304 + cb;
    // B: pixel = n0 + row -> (nimg, h, w); base addr in padded NHWC
    const int pix = n0 + row;
    const int nimg = pix / 3136;
    const int rem = pix - nimg * 3136;
    const int hh = rem / 56;
    const int ww = rem - hh * 56;
    gB[i] = xpb + (size_t)((nimg * 58 + hh) * 58 + ww) * 256 + cb;
    lA[i] = (char*)As + i * 4096 + wave * 1024;  // wave-uniform LDS base
    lB[i] = (char*)Bs + i * 4096 + wave * 1024;
  }

  // -------- compute-side LDS read offsets (bytes) --------
  const int quad = lane >> 4;
  const int x7 = lane & 7;
  const int arow = (wm * 64 + (lane & 15)) * 128;
  const int brow = (wn * 64 + (lane & 15)) * 128;
  int cko[2];
  cko[0] = ((0 + quad) ^ x7) << 4;  // ks=0: chunks 0..3
  cko[1] = ((4 + quad) ^ x7) << 4;  // ks=1: chunks 4..7

  floatx4 acc[4][4];
#pragma unroll
  for (int a = 0; a < 4; ++a)
#pragma unroll
    for (int b = 0; b < 4; ++b) acc[a][b] = (floatx4)0.f;

#pragma unroll 1
  for (int kq = 0; kq < 9; ++kq) {
    const int kh = kq / 3;
    const int kw_ = kq - kh * 3;
    const int btap = (kh * 58 + kw_) * 256;
#pragma unroll 1
    for (int ch = 0; ch < 2; ++ch) {
      const int aofs = kq * 256 + ch * 128;
      const int bofs = btap + ch * 128;
      __syncthreads();  // prev compute done before overwrite
#pragma unroll
      for (int i = 0; i < 4; ++i) {
        gload_lds16(gA[i] + aofs, lA[i]);
        gload_lds16(gB[i] + bofs, lB[i]);
      }
      __syncthreads();  // staging complete (drains vmcnt)
#pragma unroll
      for (int ks = 0; ks < 2; ++ks) {
        short8 af[4], bf[4];
#pragma unroll
        for (int mt = 0; mt < 4; ++mt)
          af[mt] = *(const short8*)((const char*)As + arow + mt * (16 * 128) + cko[ks]);
#pragma unroll
        for (int nt = 0; nt < 4; ++nt)
          bf[nt] = *(const short8*)((const char*)Bs + brow + nt * (16 * 128) + cko[ks]);
#pragma unroll
        for (int mt = 0; mt < 4; ++mt)
#pragma unroll
          for (int nt = 0; nt < 4; ++nt)
            acc[mt][nt] = __builtin_amdgcn_mfma_f32_16x16x32_bf16(
                af[mt], bf[nt], acc[mt][nt], 0, 0, 0);
      }
    }
  }

  // -------- epilogue: bias + store (C/D: row m=(lane>>4)*4+r, col n=lane&15) --------
  const int col = lane & 15;
  const int rb = (lane >> 4) * 4;
#pragma unroll
  for (int nt = 0; nt < 4; ++nt) {
    const int pix = n0 + wn * 64 + nt * 16 + col;
    const int nimg = pix / 3136;
    const int rem = pix - nimg * 3136;
    float* op = out + (size_t)nimg * (256 * 3136) + rem;
#pragma unroll
    for (int mt = 0; mt < 4; ++mt) {
      const int mb = m0 + wm * 64 + mt * 16 + rb;
#pragma unroll
      for (int r = 0; r < 4; ++r) {
        op[(size_t)(mb + r) * 3136] = acc[mt][nt][r] + bias[mb + r];
      }
    }
  }
}

// ---------- fallback: direct fp32 conv (only if ws_size too small) ----------
__global__ __launch_bounds__(256)
void direct_conv_kernel(const float* __restrict__ x, const float* __restrict__ wgt,
                        const float* __restrict__ bias, float* __restrict__ out) {
  const long t = (long)blockIdx.x * 256 + threadIdx.x;
  if (t >= 16L * 256 * 3136) return;
  const int w = t % 56;
  const int h = (t / 56) % 56;
  const int o = (t / 3136) % 256;
  const int n = t / (256L * 3136);
  float s = bias[o];
  for (int c = 0; c < 128; ++c)
    for (int kh = 0; kh < 3; ++kh) {
      const int hh = h + kh - 1;
      if (hh < 0 || hh >= 56) continue;
      for (int kw = 0; kw < 3; ++kw) {
        const int ww = w + kw - 1;
        if (ww < 0 || ww >= 56) continue;
        s += x[((size_t)(n * 128 + c) * 56 + hh) * 56 + ww] *
             wgt[((size_t)(o * 128 + c) * 3 + kh) * 3 + kw];
      }
    }
  out[t] = s;
}

extern "C" void kernel_launch(void* const* d_in, const int* in_sizes, int n_in,
                              void* d_out, int out_size, void* d_ws, size_t ws_size,
                              hipStream_t stream) {
  const float* x = (const float*)d_in[0];
  const float* w = (const float*)d_in[1];
  const float* b = (const float*)d_in[2];
  float* out = (float*)d_out;

  const size_t xp_bytes = (size_t)16 * 58 * 58 * 128 * 2;  // 13,778,944
  const size_t wt_bytes = (size_t)256 * 9 * 128 * 2;       //    589,824

  if (ws_size >= xp_bytes + wt_bytes) {
    __hip_bfloat16* xp = (__hip_bfloat16*)d_ws;
    __hip_bfloat16* wt = (__hip_bfloat16*)((char*)d_ws + xp_bytes);
    (void)hipMemsetAsync(d_ws, 0, xp_bytes, stream);  // zero pad halo (graph-safe)
    hipLaunchKernelGGL(xpose_kernel, dim3(16 * 56), dim3(256), 0, stream, x, xp);
    hipLaunchKernelGGL(wxf_kernel, dim3(1152), dim3(256), 0, stream, w, wt);
    hipLaunchKernelGGL(conv_gemm_kernel, dim3(392, 2), dim3(256), 0, stream,
                       xp, wt, b, out);
  } else {
    const long total = 16L * 256 * 3136;
    hipLaunchKernelGGL(direct_conv_kernel, dim3((unsigned)((total + 255) / 256)),
                       dim3(256), 0, stream, x, w, b, out);
  }
}

// Round 2
// 138.171 us; speedup vs baseline: 1.0344x; 1.0344x over previous
//
#include <hip/hip_runtime.h>
#include <hip/hip_bf16.h>
#include <stdint.h>

// x: [16,128,56,56] f32, w: [256,128,3,3] f32, bias: [256] f32
// out: [16,256,56,56] f32
// Implicit GEMM: M=Cout=256, N=pixels=50176, K = (kh*3+kw, c) = 1152

typedef __attribute__((ext_vector_type(8))) short short8;
typedef __attribute__((ext_vector_type(4))) float floatx4;

__device__ static inline void gload_lds16(const void* g, void* l) {
  typedef const __attribute__((address_space(1))) unsigned int* gp_t;
  typedef __attribute__((address_space(3))) unsigned int* lp_t;
  __builtin_amdgcn_global_load_lds((gp_t)(uintptr_t)g, (lp_t)(uint32_t)(uintptr_t)l,
                                   16, 0, 0);
}

// ---------- fused pre-pass: NCHW f32 -> padded NHWC bf16 (with halo zeroing)
//            + weight [256][128][3][3] f32 -> wt[256][9][128] bf16 ----------
// blocks 0..927: one (n, padded-row hp) each.  blocks 928..963: weights.
__global__ __launch_bounds__(256)
void pre_kernel(const float* __restrict__ x, const float* __restrict__ wsrc,
                __hip_bfloat16* __restrict__ xp, __hip_bfloat16* __restrict__ wt) {
  const int b = blockIdx.x;
  if (b < 16 * 58) {
    const int n = b / 58, hp = b % 58;
    __hip_bfloat16* dst = xp + (size_t)(n * 58 + hp) * 58 * 128;  // row base, col 0
    if (hp == 0 || hp == 57) {
      // zero halo row: 58*128*2 B = 928 x 16B
      const uint4 z = {0, 0, 0, 0};
      uint4* p = (uint4*)dst;
      for (int i = threadIdx.x; i < 928; i += 256) p[i] = z;
      return;
    }
    const int h = hp - 1;
    __shared__ float tile[128][57];
    const float* src = x + (size_t)n * (128 * 3136) + h * 56;
    for (int i = threadIdx.x; i < 128 * 14; i += 256) {  // float4 reads
      const int c = i / 14, q = i - c * 14;
      const float4 v = ((const float4*)(src + (size_t)c * 3136))[q];
      tile[c][4 * q + 0] = v.x;
      tile[c][4 * q + 1] = v.y;
      tile[c][4 * q + 2] = v.z;
      tile[c][4 * q + 3] = v.w;
    }
    __syncthreads();
    if (threadIdx.x < 32) {  // zero halo cols 0 and 57 (2 x 256 B)
      const uint4 z = {0, 0, 0, 0};
      const int col = (threadIdx.x >> 4) * 57;
      ((uint4*)(dst + (size_t)col * 128))[threadIdx.x & 15] = z;
    }
    __hip_bfloat16* di = dst + 128;  // col 1
    for (int i = threadIdx.x; i < 56 * 16; i += 256) {  // 16B packed writes
      const int w = i >> 4, c8 = (i & 15) * 8;
      union { uint4 u; __hip_bfloat16 hh[8]; } pk;
#pragma unroll
      for (int j = 0; j < 8; ++j) pk.hh[j] = __float2bfloat16(tile[c8 + j][w]);
      *(uint4*)(di + (size_t)w * 128 + c8) = pk.u;
    }
  } else {
    // weights: 36 blocks x 256 thr x 32 elems = 294912
    const int base = (b - 928) * 256 + threadIdx.x;
    for (int t = base; t < 256 * 9 * 128; t += 36 * 256) {
      const int c = t & 127;
      const int kq = (t >> 7) % 9;
      const int cout = t / (9 * 128);
      wt[t] = __float2bfloat16(wsrc[(size_t)(cout * 128 + c) * 9 + kq]);
    }
  }
}

// ---------- main implicit-GEMM MFMA kernel ----------
// 256 thr = 4 waves (2x2), tile 128(M) x 128(N), BK=64.
// XCD swizzle: 784 blocks = 8 XCDs x 98; each XCD gets 49 CONTIGUOUS n-tiles
// (B footprint 1.72 MB + weights 0.59 MB < 4 MB L2) so B staging hits L2 not L3.
// LDS rows = 64ch = 128B = 8x16B chunks, chunk q at position q ^ (row&7)
// (swizzle applied on the global source address; global_load_lds dest is fixed).
__global__ __launch_bounds__(256)
void conv_gemm_kernel(const __hip_bfloat16* __restrict__ xp,
                      const __hip_bfloat16* __restrict__ wt,
                      const float* __restrict__ bias,
                      float* __restrict__ out) {
  __shared__ __align__(16) __hip_bfloat16 As[128 * 64];  // [m][k] 16 KB
  __shared__ __align__(16) __hip_bfloat16 Bs[128 * 64];  // [n][k] 16 KB

  const int tid = threadIdx.x;
  const int lane = tid & 63;
  const int wave = tid >> 6;
  const int wm = wave >> 1, wn = wave & 1;

  // XCD-contiguous tile assignment
  const int id = blockIdx.x;        // 0..783
  const int xcd = id & 7;
  const int r = id >> 3;            // 0..97
  const int mt_ = r / 49;           // 0..1
  const int nt_ = xcd * 49 + (r - mt_ * 49);
  const int m0 = mt_ * 128;
  const int n0 = nt_ * 128;

  const char* wtb = (const char*)wt;
  const char* xpb = (const char*)xp;
  const char* gA[4];
  const char* gB[4];
  char* lA[4];
  char* lB[4];
#pragma unroll
  for (int i = 0; i < 4; ++i) {
    const int f = (i * 256 + tid) * 16;
    const int row = f >> 7;
    const int sub = (f >> 4) & 7;
    const int cb = (sub ^ (row & 7)) << 4;
    gA[i] = wtb + (size_t)(m0 + row) * 2304 + cb;  // wt row stride 9*128*2
    const int pix = n0 + row;
    const int nimg = pix / 3136;
    const int rem = pix - nimg * 3136;
    const int hh = rem / 56;
    const int ww = rem - hh * 56;
    gB[i] = xpb + (size_t)((nimg * 58 + hh) * 58 + ww) * 256 + cb;
    lA[i] = (char*)As + i * 4096 + wave * 1024;
    lB[i] = (char*)Bs + i * 4096 + wave * 1024;
  }

  const int quad = lane >> 4;
  const int x7 = lane & 7;
  const int arow = (wm * 64 + (lane & 15)) * 128;
  const int brow = (wn * 64 + (lane & 15)) * 128;
  int cko[2];
  cko[0] = ((0 + quad) ^ x7) << 4;
  cko[1] = ((4 + quad) ^ x7) << 4;

  floatx4 acc[4][4];
#pragma unroll
  for (int a = 0; a < 4; ++a)
#pragma unroll
    for (int c = 0; c < 4; ++c) acc[a][c] = (floatx4)0.f;

#pragma unroll 1
  for (int kq = 0; kq < 9; ++kq) {
    const int kh = kq / 3;
    const int kw_ = kq - kh * 3;
    const int btap = (kh * 58 + kw_) * 256;
#pragma unroll 1
    for (int ch = 0; ch < 2; ++ch) {
      const int aofs = kq * 256 + ch * 128;
      const int bofs = btap + ch * 128;
      __syncthreads();
#pragma unroll
      for (int i = 0; i < 4; ++i) {
        gload_lds16(gA[i] + aofs, lA[i]);
        gload_lds16(gB[i] + bofs, lB[i]);
      }
      __syncthreads();
#pragma unroll
      for (int ks = 0; ks < 2; ++ks) {
        short8 af[4], bf[4];
#pragma unroll
        for (int mt = 0; mt < 4; ++mt)
          af[mt] = *(const short8*)((const char*)As + arow + mt * (16 * 128) + cko[ks]);
#pragma unroll
        for (int nt = 0; nt < 4; ++nt)
          bf[nt] = *(const short8*)((const char*)Bs + brow + nt * (16 * 128) + cko[ks]);
#pragma unroll
        for (int mt = 0; mt < 4; ++mt)
#pragma unroll
          for (int nt = 0; nt < 4; ++nt)
            acc[mt][nt] = __builtin_amdgcn_mfma_f32_16x16x32_bf16(
                af[mt], bf[nt], acc[mt][nt], 0, 0, 0);
      }
    }
  }

  // epilogue: bias + store (C/D: row m=(lane>>4)*4+r, col n=lane&15)
  const int col = lane & 15;
  const int rb = (lane >> 4) * 4;
#pragma unroll
  for (int nt = 0; nt < 4; ++nt) {
    const int pix = n0 + wn * 64 + nt * 16 + col;
    const int nimg = pix / 3136;
    const int rem = pix - nimg * 3136;
    float* op = out + (size_t)nimg * (256 * 3136) + rem;
#pragma unroll
    for (int mt = 0; mt < 4; ++mt) {
      const int mb = m0 + wm * 64 + mt * 16 + rb;
#pragma unroll
      for (int rr = 0; rr < 4; ++rr) {
        op[(size_t)(mb + rr) * 3136] = acc[mt][nt][rr] + bias[mb + rr];
      }
    }
  }
}

// ---------- fallback: direct fp32 conv (only if ws too small) ----------
__global__ __launch_bounds__(256)
void direct_conv_kernel(const float* __restrict__ x, const float* __restrict__ wgt,
                        const float* __restrict__ bias, float* __restrict__ out) {
  const long t = (long)blockIdx.x * 256 + threadIdx.x;
  if (t >= 16L * 256 * 3136) return;
  const int w = t % 56;
  const int h = (t / 56) % 56;
  const int o = (t / 3136) % 256;
  const int n = t / (256L * 3136);
  float s = bias[o];
  for (int c = 0; c < 128; ++c)
    for (int kh = 0; kh < 3; ++kh) {
      const int hh = h + kh - 1;
      if (hh < 0 || hh >= 56) continue;
      for (int kw = 0; kw < 3; ++kw) {
        const int ww = w + kw - 1;
        if (ww < 0 || ww >= 56) continue;
        s += x[((size_t)(n * 128 + c) * 56 + hh) * 56 + ww] *
             wgt[((size_t)(o * 128 + c) * 3 + kh) * 3 + kw];
      }
    }
  out[t] = s;
}

extern "C" void kernel_launch(void* const* d_in, const int* in_sizes, int n_in,
                              void* d_out, int out_size, void* d_ws, size_t ws_size,
                              hipStream_t stream) {
  const float* x = (const float*)d_in[0];
  const float* w = (const float*)d_in[1];
  const float* b = (const float*)d_in[2];
  float* out = (float*)d_out;

  const size_t xp_bytes = (size_t)16 * 58 * 58 * 128 * 2;  // 13,778,944
  const size_t wt_bytes = (size_t)256 * 9 * 128 * 2;       //    589,824

  if (ws_size >= xp_bytes + wt_bytes) {
    __hip_bfloat16* xp = (__hip_bfloat16*)d_ws;
    __hip_bfloat16* wt = (__hip_bfloat16*)((char*)d_ws + xp_bytes);
    hipLaunchKernelGGL(pre_kernel, dim3(16 * 58 + 36), dim3(256), 0, stream,
                       x, w, xp, wt);
    hipLaunchKernelGGL(conv_gemm_kernel, dim3(784), dim3(256), 0, stream,
                       xp, wt, b, out);
  } else {
    const long total = 16L * 256 * 3136;
    hipLaunchKernelGGL(direct_conv_kernel, dim3((unsigned)((total + 255) / 256)),
                       dim3(256), 0, stream, x, w, b, out);
  }
}

// Round 4
// 132.152 us; speedup vs baseline: 1.0815x; 1.0455x over previous
//
#include <hip/hip_runtime.h>
#include <hip/hip_bf16.h>
#include <stdint.h>

// x: [16,128,56,56] f32, w: [256,128,3,3] f32, bias: [256] f32
// out: [16,256,56,56] f32
// Implicit GEMM: M=Cout=256, N=pixels=50176, K = (kh*3+kw, c) = 1152
// Round 3b: conv-aware B-patch staged ONCE per block; A double-buffered with a
// single barrier per K-step (drain slack = one full compute phase).
// (R3 compile fix: no LDS-pointer arrays — gfx950 rejects addrspacecast
//  static initializers; compute dbuf pointers arithmetically.)

typedef __attribute__((ext_vector_type(8))) short short8;
typedef __attribute__((ext_vector_type(4))) float floatx4;

__device__ static inline void gload_lds16(const void* g, void* l) {
  typedef const __attribute__((address_space(1))) unsigned int* gp_t;
  typedef __attribute__((address_space(3))) unsigned int* lp_t;
  __builtin_amdgcn_global_load_lds((gp_t)(uintptr_t)g, (lp_t)(uint32_t)(uintptr_t)l,
                                   16, 0, 0);
}

// ---------- fused pre-pass: NCHW f32 -> padded NHWC bf16 (halo zeroed)
//            + weight [256][128][3][3] f32 -> wt[256][9][128] bf16 ----------
__global__ __launch_bounds__(256)
void pre_kernel(const float* __restrict__ x, const float* __restrict__ wsrc,
                __hip_bfloat16* __restrict__ xp, __hip_bfloat16* __restrict__ wt) {
  const int b = blockIdx.x;
  if (b < 16 * 58) {
    const int n = b / 58, hp = b % 58;
    __hip_bfloat16* dst = xp + (size_t)(n * 58 + hp) * 58 * 128;
    if (hp == 0 || hp == 57) {
      const uint4 z = {0, 0, 0, 0};
      uint4* p = (uint4*)dst;
      for (int i = threadIdx.x; i < 928; i += 256) p[i] = z;
      return;
    }
    const int h = hp - 1;
    __shared__ float tile[128][57];
    const float* src = x + (size_t)n * (128 * 3136) + h * 56;
    for (int i = threadIdx.x; i < 128 * 14; i += 256) {
      const int c = i / 14, q = i - c * 14;
      const float4 v = ((const float4*)(src + (size_t)c * 3136))[q];
      tile[c][4 * q + 0] = v.x;
      tile[c][4 * q + 1] = v.y;
      tile[c][4 * q + 2] = v.z;
      tile[c][4 * q + 3] = v.w;
    }
    __syncthreads();
    if (threadIdx.x < 32) {
      const uint4 z = {0, 0, 0, 0};
      const int col = (threadIdx.x >> 4) * 57;
      ((uint4*)(dst + (size_t)col * 128))[threadIdx.x & 15] = z;
    }
    __hip_bfloat16* di = dst + 128;
    for (int i = threadIdx.x; i < 56 * 16; i += 256) {
      const int w = i >> 4, c8 = (i & 15) * 8;
      union { uint4 u; __hip_bfloat16 hh[8]; } pk;
#pragma unroll
      for (int j = 0; j < 8; ++j) pk.hh[j] = __float2bfloat16(tile[c8 + j][w]);
      *(uint4*)(di + (size_t)w * 128 + c8) = pk.u;
    }
  } else {
    const int base = (b - 928) * 256 + threadIdx.x;
    for (int t = base; t < 256 * 9 * 128; t += 36 * 256) {
      const int c = t & 127;
      const int kq = (t >> 7) % 9;
      const int cout = t / (9 * 128);
      wt[t] = __float2bfloat16(wsrc[(size_t)(cout * 128 + c) * 9 + kq]);
    }
  }
}

// ---------- main implicit-GEMM MFMA kernel ----------
// 256 thr = 4 waves (2x2 over M128 x N64). LDS: B-patch 192x256B (48 KB, staged
// once) + A dbuf 2x16 KB = 80 KB -> 2 blocks/CU.
// Patch rows = 256 B = 16 x 16B chunks, chunk c stored at slot c ^ (row&7).
// A rows = 128 B = 8 chunks, chunk c at slot c ^ (row&7) (as verified R1/R2).
__global__ __launch_bounds__(256)
void conv_gemm_kernel(const __hip_bfloat16* __restrict__ xp,
                      const __hip_bfloat16* __restrict__ wt,
                      const float* __restrict__ bias,
                      float* __restrict__ out) {
  __shared__ __align__(16) char smem[49152 + 2 * 16384];  // patch + A dbuf

  const int tid = threadIdx.x;
  const int lane = tid & 63;
  const int wave = tid >> 6;
  const int wm = wave >> 1, wn = wave & 1;

  // XCD-contiguous tiles: 1568 = 8 XCD x 196 (2 m x 98 n)
  const int id = blockIdx.x;
  const int xcd = id & 7;
  const int r = id >> 3;
  const int mt_ = r / 98;
  const int nt_ = xcd * 98 + (r - mt_ * 98);
  const int m0 = mt_ * 128;
  const int n0 = nt_ * 64;  // 64 consecutive pixels; never crosses an image

  // patch base: padded-pixel index of pixel n0 at tap (0,0)
  const int nimg0 = n0 / 3136;
  const int rem0 = n0 - nimg0 * 3136;
  const int hh0 = rem0 / 56;
  const int ww0 = rem0 - hh0 * 56;
  const int P0 = (nimg0 * 58 + hh0) * 58 + ww0;
  const char* pbase = (const char*)xp + (size_t)P0 * 256;

  // ---- prologue: stage B-patch (12 insts) + A(0) (4 insts) ----
  const char* wtb = (const char*)wt;
  const char* gA[4];
#pragma unroll
  for (int i = 0; i < 4; ++i) {
    const int f = (i * 256 + tid) * 16;
    const int rowA = f >> 7;
    const int sub = (f >> 4) & 7;
    gA[i] = wtb + (size_t)(m0 + rowA) * 2304 + ((sub ^ (rowA & 7)) << 4);
  }
#pragma unroll
  for (int i = 0; i < 12; ++i) {
    const int j = i * 256 + tid;
    const int row = j >> 4;
    const int slot = j & 15;
    gload_lds16(pbase + row * 256 + ((slot ^ (row & 7)) << 4),
                smem + i * 4096 + wave * 1024);
  }
#pragma unroll
  for (int i = 0; i < 4; ++i)
    gload_lds16(gA[i], smem + 49152 + i * 4096 + wave * 1024);

  // ---- per-lane read offsets ----
  const int col = lane & 15;
  const int quad = lane >> 4;
  const int x7 = lane & 7;
  const int arow = (wm * 64 + col) * 128;
  int cko[2];
  cko[0] = ((0 + quad) ^ x7) << 4;
  cko[1] = ((4 + quad) ^ x7) << 4;
  int rbase[2];
#pragma unroll
  for (int nt = 0; nt < 2; ++nt) {
    const int pix = n0 + wn * 32 + nt * 16 + col;
    const int ni = pix / 3136;
    const int re = pix - ni * 3136;
    const int ph = re / 56;
    const int pw = re - ph * 56;
    rbase[nt] = (ni * 58 + ph) * 58 + pw - P0;  // local patch row, tap (0,0)
  }

  floatx4 acc[4][2];
#pragma unroll
  for (int a = 0; a < 4; ++a)
#pragma unroll
    for (int c = 0; c < 2; ++c) acc[a][c] = (floatx4)0.f;

  // ---- K loop: 18 steps (9 taps x 2 half-channel chunks), ONE barrier each ----
#pragma unroll 1
  for (int s = 0; s < 18; ++s) {
    __syncthreads();  // drains A(s) loads (issued at s-1: full step of slack)
    if (s < 17) {
      const int s1 = s + 1;
      const int aofs = (s1 >> 1) * 256 + (s1 & 1) * 128;
      char* ad = smem + 49152 + ((s1 & 1) << 14) + wave * 1024;
#pragma unroll
      for (int i = 0; i < 4; ++i)
        gload_lds16(gA[i] + aofs, ad + i * 4096);
    }
    const int kq = s >> 1, ch = s & 1;
    const int kh = kq / 3;
    const int tofs = kh * 58 + (kq - kh * 3);
    const char* ab = smem + 49152 + ((s & 1) << 14);
#pragma unroll
    for (int ks = 0; ks < 2; ++ks) {
      short8 af[4], bf[2];
#pragma unroll
      for (int mt = 0; mt < 4; ++mt)
        af[mt] = *(const short8*)(ab + arow + mt * 2048 + cko[ks]);
      const int cB = ch * 8 + ks * 4 + quad;
#pragma unroll
      for (int nt = 0; nt < 2; ++nt) {
        const int rowB = rbase[nt] + tofs;
        const int pos = cB ^ (rowB & 7);
        bf[nt] = *(const short8*)(smem + rowB * 256 + (pos << 4));
      }
#pragma unroll
      for (int mt = 0; mt < 4; ++mt)
#pragma unroll
        for (int nt = 0; nt < 2; ++nt)
          acc[mt][nt] = __builtin_amdgcn_mfma_f32_16x16x32_bf16(
              af[mt], bf[nt], acc[mt][nt], 0, 0, 0);
    }
  }

  // ---- epilogue: bias + store (C/D: row m=(lane>>4)*4+r, col n=lane&15) ----
  const int rb = quad * 4;
#pragma unroll
  for (int nt = 0; nt < 2; ++nt) {
    const int pix = n0 + wn * 32 + nt * 16 + col;
    const int nimg = pix / 3136;
    const int rem = pix - nimg * 3136;
    float* op = out + (size_t)nimg * (256 * 3136) + rem;
#pragma unroll
    for (int mt = 0; mt < 4; ++mt) {
      const int mb = m0 + wm * 64 + mt * 16 + rb;
#pragma unroll
      for (int rr = 0; rr < 4; ++rr) {
        op[(size_t)(mb + rr) * 3136] = acc[mt][nt][rr] + bias[mb + rr];
      }
    }
  }
}

// ---------- fallback: direct fp32 conv (only if ws too small) ----------
__global__ __launch_bounds__(256)
void direct_conv_kernel(const float* __restrict__ x, const float* __restrict__ wgt,
                        const float* __restrict__ bias, float* __restrict__ out) {
  const long t = (long)blockIdx.x * 256 + threadIdx.x;
  if (t >= 16L * 256 * 3136) return;
  const int w = t % 56;
  const int h = (t / 56) % 56;
  const int o = (t / 3136) % 256;
  const int n = t / (256L * 3136);
  float s = bias[o];
  for (int c = 0; c < 128; ++c)
    for (int kh = 0; kh < 3; ++kh) {
      const int hh = h + kh - 1;
      if (hh < 0 || hh >= 56) continue;
      for (int kw = 0; kw < 3; ++kw) {
        const int ww = w + kw - 1;
        if (ww < 0 || ww >= 56) continue;
        s += x[((size_t)(n * 128 + c) * 56 + hh) * 56 + ww] *
             wgt[((size_t)(o * 128 + c) * 3 + kh) * 3 + kw];
      }
    }
  out[t] = s;
}

extern "C" void kernel_launch(void* const* d_in, const int* in_sizes, int n_in,
                              void* d_out, int out_size, void* d_ws, size_t ws_size,
                              hipStream_t stream) {
  const float* x = (const float*)d_in[0];
  const float* w = (const float*)d_in[1];
  const float* b = (const float*)d_in[2];
  float* out = (float*)d_out;

  const size_t xp_bytes = (size_t)16 * 58 * 58 * 128 * 2;  // 13,778,944
  const size_t wt_bytes = (size_t)256 * 9 * 128 * 2;       //    589,824
  // NOTE: last blocks' patch staging reads up to ~2 KB past xp's end — lands in
  // wt region (still inside d_ws), values never used by compute. Safe.

  if (ws_size >= xp_bytes + wt_bytes) {
    __hip_bfloat16* xp = (__hip_bfloat16*)d_ws;
    __hip_bfloat16* wt = (__hip_bfloat16*)((char*)d_ws + xp_bytes);
    hipLaunchKernelGGL(pre_kernel, dim3(16 * 58 + 36), dim3(256), 0, stream,
                       x, w, xp, wt);
    hipLaunchKernelGGL(conv_gemm_kernel, dim3(1568), dim3(256), 0, stream,
                       xp, wt, b, out);
  } else {
    const long total = 16L * 256 * 3136;
    hipLaunchKernelGGL(direct_conv_kernel, dim3((unsigned)((total + 255) / 256)),
                       dim3(256), 0, stream, x, w, b, out);
  }
}

// Round 6
// 125.768 us; speedup vs baseline: 1.1364x; 1.0508x over previous
//
#include <hip/hip_runtime.h>
#include <hip/hip_bf16.h>
#include <stdint.h>

// x: [16,128,56,56] f32, w: [256,128,3,3] f32, bias: [256] f32
// out: [16,256,56,56] f32
// Implicit GEMM: M=Cout=256, N=pixels=50176, K = (kh*3+kw, c) = 1152
// Round 5b: barrier-free K-loop. B-patch staged ONCE in LDS (48 KB, one
// barrier); A (weights) read directly L2->registers in MFMA-fragment order,
// software-pipelined one step ahead. 3 blocks/CU.
// R5 bugfix: wt2 g-group BYTE stride is 36864 (=18432 elems * 2B) — R5 used
// 18432 bytes, reading A from the wrong Cout group (absmax 12.4).

typedef __attribute__((ext_vector_type(8))) short short8;
typedef __attribute__((ext_vector_type(4))) float floatx4;

__device__ static inline void gload_lds16(const void* g, void* l) {
  typedef const __attribute__((address_space(1))) unsigned int* gp_t;
  typedef __attribute__((address_space(3))) unsigned int* lp_t;
  __builtin_amdgcn_global_load_lds((gp_t)(uintptr_t)g, (lp_t)(uint32_t)(uintptr_t)l,
                                   16, 0, 0);
}

// ---------- fused pre-pass: NCHW f32 -> padded NHWC bf16 (halo zeroed)
//   + weight f32 -> bf16 in MFMA-frag order wt2[g=m/16][kq][ch][ks][q][r][e]
//   elem strides: e=1, r=8, q=128, ks=512, ch=1024, kq=2048, g=18432
//   byte strides: r=16, q=256, ks=1024, ch=2048, kq=4096, g=36864 ----------
__global__ __launch_bounds__(256)
void pre_kernel(const float* __restrict__ x, const float* __restrict__ wsrc,
                __hip_bfloat16* __restrict__ xp, __hip_bfloat16* __restrict__ wt) {
  const int b = blockIdx.x;
  if (b < 16 * 58) {
    const int n = b / 58, hp = b % 58;
    __hip_bfloat16* dst = xp + (size_t)(n * 58 + hp) * 58 * 128;
    if (hp == 0 || hp == 57) {
      const uint4 z = {0, 0, 0, 0};
      uint4* p = (uint4*)dst;
      for (int i = threadIdx.x; i < 928; i += 256) p[i] = z;
      return;
    }
    const int h = hp - 1;
    __shared__ float tile[128][57];
    const float* src = x + (size_t)n * (128 * 3136) + h * 56;
    for (int i = threadIdx.x; i < 128 * 14; i += 256) {
      const int c = i / 14, q = i - c * 14;
      const float4 v = ((const float4*)(src + (size_t)c * 3136))[q];
      tile[c][4 * q + 0] = v.x;
      tile[c][4 * q + 1] = v.y;
      tile[c][4 * q + 2] = v.z;
      tile[c][4 * q + 3] = v.w;
    }
    __syncthreads();
    if (threadIdx.x < 32) {
      const uint4 z = {0, 0, 0, 0};
      const int col = (threadIdx.x >> 4) * 57;
      ((uint4*)(dst + (size_t)col * 128))[threadIdx.x & 15] = z;
    }
    __hip_bfloat16* di = dst + 128;
    for (int i = threadIdx.x; i < 56 * 16; i += 256) {
      const int w = i >> 4, c8 = (i & 15) * 8;
      union { uint4 u; __hip_bfloat16 hh[8]; } pk;
#pragma unroll
      for (int j = 0; j < 8; ++j) pk.hh[j] = __float2bfloat16(tile[c8 + j][w]);
      *(uint4*)(di + (size_t)w * 128 + c8) = pk.u;
    }
  } else {
    const int base = (b - 928) * 256 + threadIdx.x;
    for (int t = base; t < 256 * 9 * 128; t += 36 * 256) {
      const int e = t & 7;
      const int rr = (t >> 3) & 15;
      const int q = (t >> 7) & 3;
      const int ks = (t >> 9) & 1;
      const int ch = (t >> 10) & 1;
      const int t11 = t >> 11;
      const int kq = t11 % 9;
      const int g = t11 / 9;
      const int cout = g * 16 + rr;
      const int c = ch * 64 + ks * 32 + q * 8 + e;
      wt[t] = __float2bfloat16(wsrc[(size_t)(cout * 128 + c) * 9 + kq]);
    }
  }
}

// ---------- main implicit-GEMM MFMA kernel ----------
// 256 thr = 4 waves, each wave M32 x N64 (acc 2x4). Tile M128 x N64.
// LDS: B-patch only, 192 rows x 256 B = 48 KB -> 3 blocks/CU (12 waves).
// Patch row = 16 x 16B chunks, chunk c at slot c ^ (row&7) (verified R1-R4).
// A-frags: global_load_dwordx4 at wt2 + g*36864 + frag + lane*16 (coalesced),
// prefetched one K-step ahead in registers. K-loop has NO barriers.
__global__ __launch_bounds__(256, 3)
void conv_gemm_kernel(const __hip_bfloat16* __restrict__ xp,
                      const __hip_bfloat16* __restrict__ wt,
                      const float* __restrict__ bias,
                      float* __restrict__ out) {
  __shared__ __align__(16) char smem[49152];

  const int tid = threadIdx.x;
  const int lane = tid & 63;
  const int wave = tid >> 6;
  const int col = lane & 15;
  const int quad = lane >> 4;

  // XCD-contiguous tiles: 1568 = 8 XCD x 196 (2 m x 98 n)
  const int id = blockIdx.x;
  const int xcd = id & 7;
  const int r = id >> 3;
  const int mt_ = r / 98;
  const int nt_ = xcd * 98 + (r - mt_ * 98);
  const int m0 = mt_ * 128;
  const int n0 = nt_ * 64;  // 64 consecutive pixels; never crosses an image

  // patch base: padded-pixel index of pixel n0 at tap (0,0)
  const int nimg0 = n0 / 3136;
  const int rem0 = n0 - nimg0 * 3136;
  const int hh0 = rem0 / 56;
  const int ww0 = rem0 - hh0 * 56;
  const int P0 = (nimg0 * 58 + hh0) * 58 + ww0;
  const char* pbase = (const char*)xp + (size_t)P0 * 256;

  // ---- stage B-patch (12 async 16B insts / thread-slice) ----
#pragma unroll
  for (int i = 0; i < 12; ++i) {
    const int j = i * 256 + tid;
    const int row = j >> 4;
    const int slot = j & 15;
    gload_lds16(pbase + row * 256 + ((slot ^ (row & 7)) << 4),
                smem + i * 4096 + wave * 1024);
  }

  // ---- A-frag base pointers (per mt): wt2 + g*36864B + lane*16 ----
  const char* wtb = (const char*)wt;
  const int gbase = (m0 >> 4) + wave * 2;
  const char* pA0 = wtb + (size_t)gbase * 36864 + lane * 16;
  const char* pA1 = pA0 + 36864;
  // frag byte offset(kq,ch,ks) = kq*4096 + ch*2048 + ks*1024

  // ---- prefetch A for s=0 (kq=0, ch=0) ----
  short8 areg[2][2][2];  // [buf][mt][ks]
#pragma unroll
  for (int ks = 0; ks < 2; ++ks) {
    areg[0][0][ks] = *(const short8*)(pA0 + ks * 1024);
    areg[0][1][ks] = *(const short8*)(pA1 + ks * 1024);
  }

  // ---- per-lane patch row bases (tap (0,0)) ----
  int rbase[4];
#pragma unroll
  for (int nt = 0; nt < 4; ++nt) {
    const int pix = n0 + nt * 16 + col;
    const int ni = pix / 3136;
    const int re = pix - ni * 3136;
    const int ph = re / 56;
    const int pw = re - ph * 56;
    rbase[nt] = (ni * 58 + ph) * 58 + pw - P0;
  }

  floatx4 acc[2][4];
#pragma unroll
  for (int a = 0; a < 2; ++a)
#pragma unroll
    for (int c = 0; c < 4; ++c) acc[a][c] = (floatx4)0.f;

  __syncthreads();  // patch ready (drains vmcnt; A(0) regs also arrive)

  // ---- K loop: 18 steps, NO barriers, A pipelined one step ahead ----
#pragma unroll
  for (int s = 0; s < 18; ++s) {
    const int cur = s & 1, nxt = cur ^ 1;
    if (s < 17) {
      const int s1 = s + 1;
      const int ofs = (s1 >> 1) * 4096 + (s1 & 1) * 2048;
#pragma unroll
      for (int ks = 0; ks < 2; ++ks) {
        areg[nxt][0][ks] = *(const short8*)(pA0 + ofs + ks * 1024);
        areg[nxt][1][ks] = *(const short8*)(pA1 + ofs + ks * 1024);
      }
    }
    const int kq = s >> 1, ch = s & 1;
    const int kh = kq / 3;
    const int tofs = kh * 58 + (kq - kh * 3);
    short8 bf[4][2];
#pragma unroll
    for (int nt = 0; nt < 4; ++nt) {
      const int rowB = rbase[nt] + tofs;
#pragma unroll
      for (int ks = 0; ks < 2; ++ks) {
        const int cB = ch * 8 + ks * 4 + quad;
        const int pos = cB ^ (rowB & 7);
        bf[nt][ks] = *(const short8*)(smem + rowB * 256 + (pos << 4));
      }
    }
#pragma unroll
    for (int ks = 0; ks < 2; ++ks)
#pragma unroll
      for (int mt = 0; mt < 2; ++mt)
#pragma unroll
        for (int nt = 0; nt < 4; ++nt)
          acc[mt][nt] = __builtin_amdgcn_mfma_f32_16x16x32_bf16(
              areg[cur][mt][ks], bf[nt][ks], acc[mt][nt], 0, 0, 0);
  }

  // ---- epilogue: bias + store (C/D: row m=quad*4+rr, col n=lane&15) ----
  const int rb = quad * 4;
#pragma unroll
  for (int nt = 0; nt < 4; ++nt) {
    const int pix = n0 + nt * 16 + col;
    const int nimg = pix / 3136;
    const int rem = pix - nimg * 3136;
    float* op = out + (size_t)nimg * (256 * 3136) + rem;
#pragma unroll
    for (int mt = 0; mt < 2; ++mt) {
      const int mb = m0 + wave * 32 + mt * 16 + rb;
#pragma unroll
      for (int rr = 0; rr < 4; ++rr) {
        op[(size_t)(mb + rr) * 3136] = acc[mt][nt][rr] + bias[mb + rr];
      }
    }
  }
}

// ---------- fallback: direct fp32 conv (only if ws too small) ----------
__global__ __launch_bounds__(256)
void direct_conv_kernel(const float* __restrict__ x, const float* __restrict__ wgt,
                        const float* __restrict__ bias, float* __restrict__ out) {
  const long t = (long)blockIdx.x * 256 + threadIdx.x;
  if (t >= 16L * 256 * 3136) return;
  const int w = t % 56;
  const int h = (t / 56) % 56;
  const int o = (t / 3136) % 256;
  const int n = t / (256L * 3136);
  float s = bias[o];
  for (int c = 0; c < 128; ++c)
    for (int kh = 0; kh < 3; ++kh) {
      const int hh = h + kh - 1;
      if (hh < 0 || hh >= 56) continue;
      for (int kw = 0; kw < 3; ++kw) {
        const int ww = w + kw - 1;
        if (ww < 0 || ww >= 56) continue;
        s += x[((size_t)(n * 128 + c) * 56 + hh) * 56 + ww] *
             wgt[((size_t)(o * 128 + c) * 3 + kh) * 3 + kw];
      }
    }
  out[t] = s;
}

extern "C" void kernel_launch(void* const* d_in, const int* in_sizes, int n_in,
                              void* d_out, int out_size, void* d_ws, size_t ws_size,
                              hipStream_t stream) {
  const float* x = (const float*)d_in[0];
  const float* w = (const float*)d_in[1];
  const float* b = (const float*)d_in[2];
  float* out = (float*)d_out;

  const size_t xp_bytes = (size_t)16 * 58 * 58 * 128 * 2;  // 13,778,944
  const size_t wt_bytes = (size_t)256 * 9 * 128 * 2;       //    589,824
  // NOTE: last blocks' patch staging reads up to ~2 KB past xp's end — lands in
  // wt region (still inside d_ws), values never used by compute. Safe.

  if (ws_size >= xp_bytes + wt_bytes) {
    __hip_bfloat16* xp = (__hip_bfloat16*)d_ws;
    __hip_bfloat16* wt = (__hip_bfloat16*)((char*)d_ws + xp_bytes);
    hipLaunchKernelGGL(pre_kernel, dim3(16 * 58 + 36), dim3(256), 0, stream,
                       x, w, xp, wt);
    hipLaunchKernelGGL(conv_gemm_kernel, dim3(1568), dim3(256), 0, stream,
                       xp, wt, b, out);
  } else {
    const long total = 16L * 256 * 3136;
    hipLaunchKernelGGL(direct_conv_kernel, dim3((unsigned)((total + 255) / 256)),
                       dim3(256), 0, stream, x, w, b, out);
  }
}

// Round 7
// 124.044 us; speedup vs baseline: 1.1522x; 1.0139x over previous
//
#include <hip/hip_runtime.h>
#include <hip/hip_bf16.h>
#include <stdint.h>

// x: [16,128,56,56] f32, w: [256,128,3,3] f32, bias: [256] f32
// out: [16,256,56,56] f32
// Implicit GEMM: M=Cout=256, N=pixels=50176, K = (kh*3+kw, c) = 1152
// Round 7: fully register-pipelined K-loop. B-patch in LDS (48 KB, staged once,
// read-only after prologue -> NO barriers in loop). B ds_reads double-buffered
// one step ahead in registers; A (L2->reg) prefetched at distance 2 (3-slot
// ring) so vmcnt slack ~2 steps >= L2 latency. 3 blocks/CU.

typedef __attribute__((ext_vector_type(8))) short short8;
typedef __attribute__((ext_vector_type(4))) float floatx4;

__device__ static inline void gload_lds16(const void* g, void* l) {
  typedef const __attribute__((address_space(1))) unsigned int* gp_t;
  typedef __attribute__((address_space(3))) unsigned int* lp_t;
  __builtin_amdgcn_global_load_lds((gp_t)(uintptr_t)g, (lp_t)(uint32_t)(uintptr_t)l,
                                   16, 0, 0);
}

// ---------- fused pre-pass: NCHW f32 -> padded NHWC bf16 (halo zeroed)
//   + weight f32 -> bf16 in MFMA-frag order wt2[g=m/16][kq][ch][ks][q][r][e]
//   byte strides: r=16, q=256, ks=1024, ch=2048, kq=4096, g=36864 ----------
__global__ __launch_bounds__(256)
void pre_kernel(const float* __restrict__ x, const float* __restrict__ wsrc,
                __hip_bfloat16* __restrict__ xp, __hip_bfloat16* __restrict__ wt) {
  const int b = blockIdx.x;
  if (b < 16 * 58) {
    const int n = b / 58, hp = b % 58;
    __hip_bfloat16* dst = xp + (size_t)(n * 58 + hp) * 58 * 128;
    if (hp == 0 || hp == 57) {
      const uint4 z = {0, 0, 0, 0};
      uint4* p = (uint4*)dst;
      for (int i = threadIdx.x; i < 928; i += 256) p[i] = z;
      return;
    }
    const int h = hp - 1;
    __shared__ float tile[128][57];
    const float* src = x + (size_t)n * (128 * 3136) + h * 56;
    for (int i = threadIdx.x; i < 128 * 14; i += 256) {
      const int c = i / 14, q = i - c * 14;
      const float4 v = ((const float4*)(src + (size_t)c * 3136))[q];
      tile[c][4 * q + 0] = v.x;
      tile[c][4 * q + 1] = v.y;
      tile[c][4 * q + 2] = v.z;
      tile[c][4 * q + 3] = v.w;
    }
    __syncthreads();
    if (threadIdx.x < 32) {
      const uint4 z = {0, 0, 0, 0};
      const int col = (threadIdx.x >> 4) * 57;
      ((uint4*)(dst + (size_t)col * 128))[threadIdx.x & 15] = z;
    }
    __hip_bfloat16* di = dst + 128;
    for (int i = threadIdx.x; i < 56 * 16; i += 256) {
      const int w = i >> 4, c8 = (i & 15) * 8;
      union { uint4 u; __hip_bfloat16 hh[8]; } pk;
#pragma unroll
      for (int j = 0; j < 8; ++j) pk.hh[j] = __float2bfloat16(tile[c8 + j][w]);
      *(uint4*)(di + (size_t)w * 128 + c8) = pk.u;
    }
  } else {
    const int base = (b - 928) * 256 + threadIdx.x;
    for (int t = base; t < 256 * 9 * 128; t += 36 * 256) {
      const int e = t & 7;
      const int rr = (t >> 3) & 15;
      const int q = (t >> 7) & 3;
      const int ks = (t >> 9) & 1;
      const int ch = (t >> 10) & 1;
      const int t11 = t >> 11;
      const int kq = t11 % 9;
      const int g = t11 / 9;
      const int cout = g * 16 + rr;
      const int c = ch * 64 + ks * 32 + q * 8 + e;
      wt[t] = __float2bfloat16(wsrc[(size_t)(cout * 128 + c) * 9 + kq]);
    }
  }
}

// ---------- main implicit-GEMM MFMA kernel ----------
// 256 thr = 4 waves, each wave M32 x N64 (acc 2x4). Tile M128 x N64.
// LDS: B-patch only, 192 rows x 256 B = 48 KB -> 3 blocks/CU (12 waves).
// Patch row = 16 x 16B chunks, chunk c at slot c ^ (row&7) (verified R1-R6).
__global__ __launch_bounds__(256, 3)
void conv_gemm_kernel(const __hip_bfloat16* __restrict__ xp,
                      const __hip_bfloat16* __restrict__ wt,
                      const float* __restrict__ bias,
                      float* __restrict__ out) {
  __shared__ __align__(16) char smem[49152];

  const int tid = threadIdx.x;
  const int lane = tid & 63;
  const int wave = tid >> 6;
  const int col = lane & 15;
  const int quad = lane >> 4;

  // XCD-contiguous tiles: 1568 = 8 XCD x 196 (2 m x 98 n)
  const int id = blockIdx.x;
  const int xcd = id & 7;
  const int r = id >> 3;
  const int mt_ = r / 98;
  const int nt_ = xcd * 98 + (r - mt_ * 98);
  const int m0 = mt_ * 128;
  const int n0 = nt_ * 64;  // 64 consecutive pixels; never crosses an image

  // patch base: padded-pixel index of pixel n0 at tap (0,0)
  const int nimg0 = n0 / 3136;
  const int rem0 = n0 - nimg0 * 3136;
  const int hh0 = rem0 / 56;
  const int ww0 = rem0 - hh0 * 56;
  const int P0 = (nimg0 * 58 + hh0) * 58 + ww0;
  const char* pbase = (const char*)xp + (size_t)P0 * 256;

  // ---- stage B-patch (12 async 16B insts / thread-slice) ----
#pragma unroll
  for (int i = 0; i < 12; ++i) {
    const int j = i * 256 + tid;
    const int row = j >> 4;
    const int slot = j & 15;
    gload_lds16(pbase + row * 256 + ((slot ^ (row & 7)) << 4),
                smem + i * 4096 + wave * 1024);
  }

  // ---- A-frag base pointers: wt2 + g*36864B + lane*16 ----
  const char* wtb = (const char*)wt;
  const int gbase = (m0 >> 4) + wave * 2;
  const char* pA0 = wtb + (size_t)gbase * 36864 + lane * 16;
  const char* pA1 = pA0 + 36864;
  // frag byte offset(kq,ch,ks) = kq*4096 + ch*2048 + ks*1024

  // ---- prefetch A for s=0 and s=1 (3-slot ring, distance 2) ----
  short8 areg[3][2][2];  // [ring slot][mt][ks]
#pragma unroll
  for (int s0 = 0; s0 < 2; ++s0) {
    const int ofs = (s0 & 1) * 2048;  // s0=0 -> 0, s0=1 -> 2048 (kq=0)
#pragma unroll
    for (int ks = 0; ks < 2; ++ks) {
      areg[s0][0][ks] = *(const short8*)(pA0 + ofs + ks * 1024);
      areg[s0][1][ks] = *(const short8*)(pA1 + ofs + ks * 1024);
    }
  }

  // ---- per-lane patch row bases (tap (0,0)) ----
  int rbase[4];
#pragma unroll
  for (int nt = 0; nt < 4; ++nt) {
    const int pix = n0 + nt * 16 + col;
    const int ni = pix / 3136;
    const int re = pix - ni * 3136;
    const int ph = re / 56;
    const int pw = re - ph * 56;
    rbase[nt] = (ni * 58 + ph) * 58 + pw - P0;
  }

  floatx4 acc[2][4];
#pragma unroll
  for (int a = 0; a < 2; ++a)
#pragma unroll
    for (int c = 0; c < 4; ++c) acc[a][c] = (floatx4)0.f;

  __syncthreads();  // patch ready (drains vmcnt; A(0..1) regs also arrive)

  // ---- preload B(0) from LDS into register buffer 0 ----
  short8 bfr[2][4][2];  // [buf][nt][ks]
#pragma unroll
  for (int nt = 0; nt < 4; ++nt) {
    const int rowB = rbase[nt];  // tap (0,0), tofs = 0
#pragma unroll
    for (int ks = 0; ks < 2; ++ks) {
      const int cB = ks * 4 + quad;  // ch = 0
      const int pos = cB ^ (rowB & 7);
      bfr[0][nt][ks] = *(const short8*)(smem + rowB * 256 + (pos << 4));
    }
  }

  // ---- K loop: 18 steps, NO barriers; A at distance 2, B at distance 1 ----
#pragma unroll
  for (int s = 0; s < 18; ++s) {
    if (s < 16) {  // issue A(s+2) into ring slot (s+2)%3
      const int s2 = s + 2;
      const int ofs = (s2 >> 1) * 4096 + (s2 & 1) * 2048;
      const int slot = s2 % 3;
#pragma unroll
      for (int ks = 0; ks < 2; ++ks) {
        areg[slot][0][ks] = *(const short8*)(pA0 + ofs + ks * 1024);
        areg[slot][1][ks] = *(const short8*)(pA1 + ofs + ks * 1024);
      }
    }
    if (s < 17) {  // issue B(s+1) ds_reads into buffer (s+1)&1
      const int s1 = s + 1;
      const int kq1 = s1 >> 1, ch1 = s1 & 1;
      const int kh1 = kq1 / 3;
      const int tofs1 = kh1 * 58 + (kq1 - kh1 * 3);
      const int nb = s1 & 1;
#pragma unroll
      for (int nt = 0; nt < 4; ++nt) {
        const int rowB = rbase[nt] + tofs1;
#pragma unroll
        for (int ks = 0; ks < 2; ++ks) {
          const int cB = ch1 * 8 + ks * 4 + quad;
          const int pos = cB ^ (rowB & 7);
          bfr[nb][nt][ks] = *(const short8*)(smem + rowB * 256 + (pos << 4));
        }
      }
    }
    const int ca = s % 3, cb = s & 1;
#pragma unroll
    for (int ks = 0; ks < 2; ++ks)
#pragma unroll
      for (int mt = 0; mt < 2; ++mt)
#pragma unroll
        for (int nt = 0; nt < 4; ++nt)
          acc[mt][nt] = __builtin_amdgcn_mfma_f32_16x16x32_bf16(
              areg[ca][mt][ks], bfr[cb][nt][ks], acc[mt][nt], 0, 0, 0);
  }

  // ---- epilogue: bias + store (C/D: row m=quad*4+rr, col n=lane&15) ----
  const int rb = quad * 4;
#pragma unroll
  for (int nt = 0; nt < 4; ++nt) {
    const int pix = n0 + nt * 16 + col;
    const int nimg = pix / 3136;
    const int rem = pix - nimg * 3136;
    float* op = out + (size_t)nimg * (256 * 3136) + rem;
#pragma unroll
    for (int mt = 0; mt < 2; ++mt) {
      const int mb = m0 + wave * 32 + mt * 16 + rb;
#pragma unroll
      for (int rr = 0; rr < 4; ++rr) {
        op[(size_t)(mb + rr) * 3136] = acc[mt][nt][rr] + bias[mb + rr];
      }
    }
  }
}

// ---------- fallback: direct fp32 conv (only if ws too small) ----------
__global__ __launch_bounds__(256)
void direct_conv_kernel(const float* __restrict__ x, const float* __restrict__ wgt,
                        const float* __restrict__ bias, float* __restrict__ out) {
  const long t = (long)blockIdx.x * 256 + threadIdx.x;
  if (t >= 16L * 256 * 3136) return;
  const int w = t % 56;
  const int h = (t / 56) % 56;
  const int o = (t / 3136) % 256;
  const int n = t / (256L * 3136);
  float s = bias[o];
  for (int c = 0; c < 128; ++c)
    for (int kh = 0; kh < 3; ++kh) {
      const int hh = h + kh - 1;
      if (hh < 0 || hh >= 56) continue;
      for (int kw = 0; kw < 3; ++kw) {
        const int ww = w + kw - 1;
        if (ww < 0 || ww >= 56) continue;
        s += x[((size_t)(n * 128 + c) * 56 + hh) * 56 + ww] *
             wgt[((size_t)(o * 128 + c) * 3 + kh) * 3 + kw];
      }
    }
  out[t] = s;
}

extern "C" void kernel_launch(void* const* d_in, const int* in_sizes, int n_in,
                              void* d_out, int out_size, void* d_ws, size_t ws_size,
                              hipStream_t stream) {
  const float* x = (const float*)d_in[0];
  const float* w = (const float*)d_in[1];
  const float* b = (const float*)d_in[2];
  float* out = (float*)d_out;

  const size_t xp_bytes = (size_t)16 * 58 * 58 * 128 * 2;  // 13,778,944
  const size_t wt_bytes = (size_t)256 * 9 * 128 * 2;       //    589,824
  // NOTE: last blocks' patch staging reads up to ~2 KB past xp's end — lands in
  // wt region (still inside d_ws), values never used by compute. Safe.

  if (ws_size >= xp_bytes + wt_bytes) {
    __hip_bfloat16* xp = (__hip_bfloat16*)d_ws;
    __hip_bfloat16* wt = (__hip_bfloat16*)((char*)d_ws + xp_bytes);
    hipLaunchKernelGGL(pre_kernel, dim3(16 * 58 + 36), dim3(256), 0, stream,
                       x, w, xp, wt);
    hipLaunchKernelGGL(conv_gemm_kernel, dim3(1568), dim3(256), 0, stream,
                       xp, wt, b, out);
  } else {
    const long total = 16L * 256 * 3136;
    hipLaunchKernelGGL(direct_conv_kernel, dim3((unsigned)((total + 255) / 256)),
                       dim3(256), 0, stream, x, w, b, out);
  }
}